// Round 17
// baseline (231.200 us; speedup 1.0000x reference)
//
#include <hip/hip_runtime.h>
#include <math.h>
#include <limits.h>

#define NB 16
#define NC 21
#define NANCH 65536
#define NM 20

#define POS_THR 0.5f
#define NEG_THR 0.4f
#define F_ALPHA 0.25f
#define MIN_POS_TOPK 10
#define NEG_POS_RATIO 3

#define QT 0.125f        // top-10 candidate gather threshold (q >= QT)
#define ST 0.015625f     // neg-cut candidate gather threshold (score < 1/64)
#define QCAP 4096
#define SCAP 4096
#define APT 2
#define IOU_TPB 256

// ---------- K0: zero the small control block ----------
__global__ void k_zero(int* scal, float* sums) {
  int t = threadIdx.x;
  if (t < 6 * NB) scal[t] = 0;          // pos_cnt, neg_cnt, qcnt, scnt, flagq, flags
  if (t < 3 * NB) sums[t] = 0.0f;
}

// wave-aggregated list append: one atomic per wave per call
__device__ __forceinline__ void wave_append(bool want, int lane,
                                            int* cnt, unsigned* kb, int* ki,
                                            int cap, unsigned bits, int n) {
  unsigned long long m = __ballot(want);
  if (!m) return;
  int leader = __ffsll((long long)m) - 1;
  int base = 0;
  if (lane == leader) base = atomicAdd(cnt, __popcll(m));
  base = __shfl(base, leader, 64);
  if (want) {
    int slot = base + __popcll(m & ((1ULL << lane) - 1ULL));
    if (slot < cap) { kb[slot] = bits; ki[slot] = n; }
  }
}

// ---------- K1: decode + IoU max/argmax + ballot counts + threshold gathers ----------
__global__ __launch_bounds__(IOU_TPB)
void k_iou(const float* __restrict__ reg, const float* __restrict__ anchors,
           const float* __restrict__ tb, const float* __restrict__ scores,
           float* __restrict__ miou, int* __restrict__ midx,
           int* __restrict__ pos_cnt, int* __restrict__ neg_cnt,
           unsigned* __restrict__ qcb, int* __restrict__ qci, int* __restrict__ qcnt,
           unsigned* __restrict__ scb, int* __restrict__ sci, int* __restrict__ scnt) {
  __shared__ float4 tbs4[NM];
  __shared__ float  tarea[NM];
  int b   = blockIdx.x >> 7;           // 128 blocks per image
  int blk = blockIdx.x & 127;
  int n0  = (blk << 9) + threadIdx.x;  // 512 anchors per block
  if (threadIdx.x < NM) {
    float4 t4 = ((const float4*)tb)[b * NM + threadIdx.x];
    tbs4[threadIdx.x] = t4;
    tarea[threadIdx.x] = (t4.z - t4.x) * (t4.w - t4.y);
  }
  __syncthreads();

  float dv[APT][4];
  float areaA[APT];
  #pragma unroll
  for (int j = 0; j < APT; ++j) {
    int n = n0 + j * IOU_TPB;
    float4 a4 = ((const float4*)anchors)[n];
    float aw = a4.z - a4.x, ah = a4.w - a4.y;
    float acx = a4.x + 0.5f * aw, acy = a4.y + 0.5f * ah;
    size_t rb = ((size_t)b * 4) * NANCH + n;
    float rx = reg[rb];
    float ry = reg[rb + (size_t)NANCH];
    float rw = reg[rb + 2 * (size_t)NANCH];
    float rh = reg[rb + 3 * (size_t)NANCH];
    float cx = acx + rx * aw, cy = acy + ry * ah;
    float w = aw * expf(rw), h = ah * expf(rh);
    dv[j][0] = cx - 0.5f * w;
    dv[j][1] = cy - 0.5f * h;
    dv[j][2] = cx + 0.5f * w;
    dv[j][3] = cy + 0.5f * h;
    areaA[j] = (dv[j][2] - dv[j][0]) * (dv[j][3] - dv[j][1]);
  }

  float bI[APT], bU[APT];
  int   bM[APT];
  {
    float4 t = tbs4[0];
    float ab = tarea[0];
    #pragma unroll
    for (int j = 0; j < APT; ++j) {
      float lx = fmaxf(dv[j][0], t.x), ly = fmaxf(dv[j][1], t.y);
      float rx2 = fminf(dv[j][2], t.z), ry2 = fminf(dv[j][3], t.w);
      float iw = fmaxf(rx2 - lx, 0.0f), ih = fmaxf(ry2 - ly, 0.0f);
      float inter = iw * ih;
      bI[j] = inter;
      bU[j] = areaA[j] + ab - inter;
      bM[j] = 0;
    }
  }
  #pragma unroll
  for (int m = 1; m < NM; ++m) {
    float4 t = tbs4[m];
    float ab = tarea[m];
    #pragma unroll
    for (int j = 0; j < APT; ++j) {
      float lx = fmaxf(dv[j][0], t.x), ly = fmaxf(dv[j][1], t.y);
      float rx2 = fminf(dv[j][2], t.z), ry2 = fminf(dv[j][3], t.w);
      float iw = fmaxf(rx2 - lx, 0.0f), ih = fmaxf(ry2 - ly, 0.0f);
      float inter = iw * ih;
      float uni = areaA[j] + ab - inter;
      // inter/uni > bI/bU  <=>  inter*bU > bI*uni (both unions > 0)
      if (inter * bU[j] > bI[j] * uni) { bI[j] = inter; bU[j] = uni; bM[j] = m; }
    }
  }

  int lane = threadIdx.x & 63;
  int cp = 0, cn = 0;
  #pragma unroll
  for (int j = 0; j < APT; ++j) {
    int n = n0 + j * IOU_TPB;
    size_t idx = (size_t)b * NANCH + n;
    float q = bI[j] / fmaxf(bU[j], 1e-7f);   // IEEE, matches reference
    miou[idx] = q;
    midx[idx] = bM[j];
    bool p  = (q >= POS_THR);
    bool ng = (q < NEG_THR);
    cp += __popcll(__ballot(p));
    cn += __popcll(__ballot(ng));
    // top-10 candidate gather (wave-aggregated; q>=0 so bit order == value order)
    wave_append(q >= QT, lane, &qcnt[b],
                qcb + (size_t)b * QCAP, qci + (size_t)b * QCAP,
                QCAP, __float_as_uint(q), n);
    // neg-cut candidate gather (wave-aggregated)
    float s = ng ? scores[idx] : 1.0f;
    wave_append(ng && s < ST, lane, &scnt[b],
                scb + (size_t)b * SCAP, sci + (size_t)b * SCAP,
                SCAP, __float_as_uint(s), n);
  }
  if (lane == 0) {
    if (cp) atomicAdd(&pos_cnt[b], cp);
    if (cn) atomicAdd(&neg_cnt[b], cn);
  }
}

// bitonic ascending sort of key[0..S) in LDS, S = pow2, 1024 threads
__device__ __forceinline__ void bitonic_sort(unsigned long long* key, int S) {
  for (int kk = 2; kk <= S; kk <<= 1) {
    for (int jj = kk >> 1; jj > 0; jj >>= 1) {
      for (int i = threadIdx.x; i < S; i += 1024) {
        int ixj = i ^ jj;
        if (ixj > i) {
          bool up = ((i & kk) == 0);
          unsigned long long a = key[i], c = key[ixj];
          if ((a > c) == up) { key[i] = c; key[ixj] = a; }
        }
      }
      __syncthreads();
    }
  }
}

// ---------- K2: blocks 0..15 exact top-10 (bitonic), 16..31 exact neg cut (bitonic) ----------
__global__ __launch_bounds__(1024)
void k_sel(const unsigned* __restrict__ qcb, const int* __restrict__ qci,
           const int* __restrict__ qcnt,
           const unsigned* __restrict__ scb, const int* __restrict__ sci,
           const int* __restrict__ scnt,
           const int* __restrict__ pos_cnt, const int* __restrict__ neg_cnt,
           int* __restrict__ num_pos, int* __restrict__ use_fb,
           int* __restrict__ subsample, int* __restrict__ total_samples,
           int* __restrict__ top10,
           unsigned* __restrict__ vbits_out, int* __restrict__ idx_cut,
           int* __restrict__ flagq, int* __restrict__ flags) {
  __shared__ unsigned long long key[QCAP];
  if (blockIdx.x < NB) {
    int b = blockIdx.x;
    int pc = pos_cnt[b], nc = neg_cnt[b];
    int fb = (pc < MIN_POS_TOPK) ? 1 : 0;
    int np = fb ? MIN_POS_TOPK : pc;
    int k = NEG_POS_RATIO * np;
    int sub = (nc > k) ? 1 : 0;
    if (threadIdx.x == 0) {
      num_pos[b] = np; use_fb[b] = fb; subsample[b] = sub;
      total_samples[b] = sub ? (np + k) : (np + nc);
    }
    if (!fb) return;                       // top10 unused by k_loss
    int E = qcnt[b];
    if (E < MIN_POS_TOPK || E > QCAP) {    // candidate set insufficient -> rescue
      if (threadIdx.x == 0) flagq[b] = 1;
      return;
    }
    int S = 16; while (S < E) S <<= 1;
    for (int j = threadIdx.x; j < S; j += 1024) {
      key[j] = (j < E)
        ? ((unsigned long long)(~qcb[(size_t)b * QCAP + j]) << 32) | (unsigned)qci[(size_t)b * QCAP + j]
        : 0xFFFFFFFFFFFFFFFFULL;
    }
    __syncthreads();
    bitonic_sort(key, S);
    if (threadIdx.x < MIN_POS_TOPK)
      top10[b * MIN_POS_TOPK + threadIdx.x] = (int)(unsigned)(key[threadIdx.x] & 0xFFFFFFFFu);
  } else {
    int b = blockIdx.x - NB;
    int pc = pos_cnt[b], nc = neg_cnt[b];
    int np = (pc < MIN_POS_TOPK) ? MIN_POS_TOPK : pc;
    int k = NEG_POS_RATIO * np;
    if (nc <= k) {
      if (threadIdx.x == 0) { vbits_out[b] = 0u; idx_cut[b] = -1; }
      return;
    }
    int E = scnt[b];
    if (E < k || E > SCAP) {               // candidate set insufficient -> rescue
      if (threadIdx.x == 0) flags[b] = 1;
      return;
    }
    int S = 16; while (S < E) S <<= 1;
    for (int j = threadIdx.x; j < S; j += 1024) {
      key[j] = (j < E)
        ? ((unsigned long long)scb[(size_t)b * SCAP + j] << 32) | (unsigned)sci[(size_t)b * SCAP + j]
        : 0xFFFFFFFFFFFFFFFFULL;
    }
    __syncthreads();
    bitonic_sort(key, S);
    if (threadIdx.x == 0) {
      unsigned long long kv = key[k - 1];
      vbits_out[b] = (unsigned)(kv >> 32);
      idx_cut[b]  = (int)(unsigned)(kv & 0xFFFFFFFFu);
    }
  }
}

// ---------- K3: exact rescue for flagged images (early-exits when none) ----------
__global__ __launch_bounds__(1024)
void k_rescue(const float* __restrict__ miou, const float* __restrict__ scores,
              const int* __restrict__ flagq, const int* __restrict__ flags,
              const int* __restrict__ num_pos,
              int* __restrict__ top10,
              unsigned* __restrict__ vbits_out, int* __restrict__ idx_cut) {
  int b = blockIdx.x;
  int fq = flagq[b], fs = flags[b];
  if (!fq && !fs) return;
  const float* mi = miou + (size_t)b * NANCH;
  const float* sc = scores + (size_t)b * NANCH;
  int lane = threadIdx.x & 63;
  int wid  = threadIdx.x >> 6;

  __shared__ unsigned long long buf64[4096];   // shared by both phases
  __shared__ unsigned qh[64];
  __shared__ int s_thr, s_cnt, s_ok;

  if (fq) {
    // adaptive threshold: tightest t with #{q_bin64 >= t} >= 10, count <= 4096
    if (threadIdx.x < 64) qh[threadIdx.x] = 0u;
    if (threadIdx.x == 0) { s_cnt = 0; s_ok = 0; }
    __syncthreads();
    for (int n = threadIdx.x; n < NANCH; n += 1024) {
      float q = mi[n];
      if (q >= QT) {
        unsigned bin = (unsigned)(q * 64.0f);
        if (bin > 63u) bin = 63u;
        atomicAdd(&qh[bin], 1u);
      }
    }
    __syncthreads();
    if (threadIdx.x == 0) {
      unsigned cum = 0; int t = -1;
      for (int i = 63; i >= 8; --i) {          // largest t with suffix >= 10
        cum += qh[i];
        if (cum >= (unsigned)MIN_POS_TOPK) { t = i; break; }
      }
      if (t < 0) t = 8;
      unsigned c = 0;
      for (int i = t; i < 64; ++i) c += qh[i];
      s_thr = t; s_cnt = 0;
      s_ok = (c >= (unsigned)MIN_POS_TOPK && c <= 4096u) ? 1 : 0;
    }
    __syncthreads();
    if (s_ok) {
      int t = s_thr;
      for (int n = threadIdx.x; n < NANCH; n += 1024) {
        float q = mi[n];
        if (q >= QT) {
          unsigned bin = (unsigned)(q * 64.0f);
          if (bin > 63u) bin = 63u;
          if ((int)bin >= t) {
            int slot = atomicAdd(&s_cnt, 1);
            if (slot < 4096)
              buf64[slot] = ((unsigned long long)(~__float_as_uint(q)) << 32) | (unsigned)n;
          }
        }
      }
      __syncthreads();
      int E = s_cnt < 4096 ? s_cnt : 4096;
      int S = 16; while (S < E) S <<= 1;
      for (int j = threadIdx.x; j < S; j += 1024)
        if (j >= E) buf64[j] = 0xFFFFFFFFFFFFFFFFULL;
      __syncthreads();
      bitonic_sort(buf64, S);
      if (threadIdx.x < MIN_POS_TOPK)
        top10[b * MIN_POS_TOPK + threadIdx.x] = (int)(unsigned)(buf64[threadIdx.x] & 0xFFFFFFFFu);
    } else {
      // ultra-fallback (structurally ~never): exact 10-iteration scan
      __shared__ float fsv[16];
      __shared__ int   fsi[16];
      __shared__ int   fsel[MIN_POS_TOPK];
      for (int it = 0; it < MIN_POS_TOPK; ++it) {
        float bv = -1.0f; int bi = NANCH;
        for (int n = threadIdx.x; n < NANCH; n += 1024) {
          bool skip = false;
          for (int s2 = 0; s2 < it; ++s2) if (fsel[s2] == n) skip = true;
          if (skip) continue;
          float v = mi[n];
          if (v > bv || (v == bv && n < bi)) { bv = v; bi = n; }
        }
        #pragma unroll
        for (int m = 32; m >= 1; m >>= 1) {
          float ov = __shfl_xor(bv, m, 64);
          int   oi = __shfl_xor(bi, m, 64);
          if (ov > bv || (ov == bv && oi < bi)) { bv = ov; bi = oi; }
        }
        if (lane == 0) { fsv[wid] = bv; fsi[wid] = bi; }
        __syncthreads();
        if (threadIdx.x == 0) {
          float bb = -1.0f; int bj = NANCH;
          for (int w = 0; w < 16; ++w)
            if (fsv[w] > bb || (fsv[w] == bb && fsi[w] < bj)) { bb = fsv[w]; bj = fsi[w]; }
          fsel[it] = bj;
        }
        __syncthreads();
      }
      if (threadIdx.x < MIN_POS_TOPK) top10[b * MIN_POS_TOPK + threadIdx.x] = fsel[threadIdx.x];
    }
    __syncthreads();
  }

  if (fs) {
    // exact neg cut via 256-bin value hist, then bitonic over the boundary bucket
    __shared__ unsigned lsh[256];
    __shared__ int s_bkt, s_below, s_cnt2;
    int k = NEG_POS_RATIO * num_pos[b];
    if (threadIdx.x < 256) lsh[threadIdx.x] = 0u;
    if (threadIdx.x == 0) s_cnt2 = 0;
    __syncthreads();
    for (int n = threadIdx.x; n < NANCH; n += 1024) {
      if (mi[n] < NEG_THR) {
        unsigned bin = (unsigned)(sc[n] * 256.0f);
        if (bin > 255u) bin = 255u;
        atomicAdd(&lsh[bin], 1u);
      }
    }
    __syncthreads();
    if (threadIdx.x == 0) {
      unsigned cum = 0; int bkt = 255;
      for (int t = 0; t < 256; ++t) {
        if (cum + lsh[t] >= (unsigned)k) { bkt = t; break; }
        cum += lsh[t];
      }
      s_bkt = bkt; s_below = (int)cum;
    }
    __syncthreads();
    int bkt = s_bkt;
    for (int n = threadIdx.x; n < NANCH; n += 1024) {
      if (mi[n] < NEG_THR) {
        float s = sc[n];
        unsigned bin = (unsigned)(s * 256.0f);
        if (bin > 255u) bin = 255u;
        if ((int)bin == bkt) {
          int slot = atomicAdd(&s_cnt2, 1);
          if (slot < 4096)
            buf64[slot] = ((unsigned long long)__float_as_uint(s) << 32) | (unsigned)n;
        }
      }
    }
    __syncthreads();
    int E = s_cnt2 < 4096 ? s_cnt2 : 4096;
    int S = 16; while (S < E) S <<= 1;
    for (int j = threadIdx.x; j < S; j += 1024)
      if (j >= E) buf64[j] = 0xFFFFFFFFFFFFFFFFULL;
    __syncthreads();
    bitonic_sort(buf64, S);
    int r = k - s_below;                 // 1-based rank within bucket
    if (threadIdx.x == 0 && r >= 1 && r <= E) {
      unsigned long long kv = buf64[r - 1];
      vbits_out[b] = (unsigned)(kv >> 32);
      idx_cut[b]  = (int)(unsigned)(kv & 0xFFFFFFFFu);
    }
  }
}

// ---------- K4: per-anchor loss accumulation ----------
__global__ __launch_bounds__(256)
void k_loss(const float* __restrict__ cls, const float* __restrict__ reg,
            const float* __restrict__ anchors, const float* __restrict__ tb,
            const int* __restrict__ tl, const float* __restrict__ scores,
            const float* __restrict__ miou, const int* __restrict__ midx,
            const int* __restrict__ use_fb, const int* __restrict__ top10,
            const int* __restrict__ subsample, const unsigned* __restrict__ vbits,
            const int* __restrict__ idx_cut,
            float* __restrict__ sums /* [NB][3] : pos, neg, reg */) {
  int b = blockIdx.x >> 8;
  int n = ((blockIdx.x & 255) << 8) | threadIdx.x;
  __shared__ int s_top10[MIN_POS_TOPK];
  __shared__ int s_usefb, s_sub, s_cut;
  __shared__ unsigned s_vb;
  __shared__ float accp, accn, accr;
  if (threadIdx.x < MIN_POS_TOPK) s_top10[threadIdx.x] = top10[b * MIN_POS_TOPK + threadIdx.x];
  if (threadIdx.x == 0) {
    s_usefb = use_fb[b]; s_sub = subsample[b]; s_cut = idx_cut[b]; s_vb = vbits[b];
    accp = 0.0f; accn = 0.0f; accr = 0.0f;
  }
  __syncthreads();

  size_t idx = (size_t)b * NANCH + n;
  float mi = miou[idx];

  bool pos;
  if (s_usefb) {
    pos = false;
    #pragma unroll
    for (int i = 0; i < MIN_POS_TOPK; ++i) pos |= (s_top10[i] == n);
  } else {
    pos = (mi >= POS_THR);
  }
  bool neg = (mi < NEG_THR);
  bool nsel = false;
  if (neg) {
    if (!s_sub) nsel = true;
    else {
      unsigned sb = __float_as_uint(scores[idx]);
      nsel = (sb < s_vb) || (sb == s_vb && n <= s_cut);
    }
  }

  float cp = 0.0f, cn = 0.0f, rg = 0.0f;
  if (pos || nsel) {
    int mx = 0, t = 0;
    if (pos) { mx = midx[idx]; t = tl[b * NM + mx]; }
    size_t cb = ((size_t)b * NC) * NANCH + n;
    float mxl = -3.0e38f, l0 = 0.0f, lt = 0.0f;
    for (int c = 0; c < NC; ++c) {
      float l = cls[cb + (size_t)c * NANCH];
      if (c == 0) l0 = l;
      if (c == t) lt = l;
      mxl = fmaxf(mxl, l);
    }
    float se = 0.0f;
    for (int c = 0; c < NC; ++c) {
      float l = cls[cb + (size_t)c * NANCH];
      se += expf(l - mxl);
    }
    float lse = mxl + logf(se);
    if (nsel) {
      float ce = lse - l0;
      float pt = expf(-ce);
      float om = 1.0f - pt;
      cn = F_ALPHA * om * om * ce;
    }
    if (pos) {
      float ce = lse - lt;
      float pt = expf(-ce);
      float om = 1.0f - pt;
      cp = F_ALPHA * om * om * ce;
      // decode + GIoU vs matched GT
      const float4 a4 = ((const float4*)anchors)[n];
      float aw = a4.z - a4.x, ah = a4.w - a4.y;
      float acx = a4.x + 0.5f * aw, acy = a4.y + 0.5f * ah;
      size_t rb = ((size_t)b * 4) * NANCH + n;
      float rx = reg[rb];
      float ry = reg[rb + (size_t)NANCH];
      float rw = reg[rb + 2 * (size_t)NANCH];
      float rh = reg[rb + 3 * (size_t)NANCH];
      float ccx = acx + rx * aw, ccy = acy + ry * ah;
      float w = aw * expf(rw), h = ah * expf(rh);
      float d0 = ccx - 0.5f * w, d1 = ccy - 0.5f * h;
      float d2 = ccx + 0.5f * w, d3 = ccy + 0.5f * h;
      const float* g = tb + ((size_t)b * NM + mx) * 4;
      float gx1 = g[0], gy1 = g[1], gx2 = g[2], gy2 = g[3];
      float area_a = (d2 - d0) * (d3 - d1);
      float area_b = (gx2 - gx1) * (gy2 - gy1);
      float lx = fmaxf(d0, gx1), ly = fmaxf(d1, gy1);
      float rx2 = fminf(d2, gx2), ry2 = fminf(d3, gy2);
      float iw = fmaxf(rx2 - lx, 0.0f), ih = fmaxf(ry2 - ly, 0.0f);
      float inter = iw * ih;
      float uni = area_a + area_b - inter;
      float iou = inter / fmaxf(uni, 1e-7f);
      float ex1 = fminf(d0, gx1), ey1 = fminf(d1, gy1);
      float ex2 = fmaxf(d2, gx2), ey2 = fmaxf(d3, gy2);
      float ew = fmaxf(ex2 - ex1, 0.0f), eh = fmaxf(ey2 - ey1, 0.0f);
      float enc = ew * eh;
      float giou = iou - (enc - uni) / fmaxf(enc, 1e-7f);
      rg = 1.0f - giou;
    }
  }

  if (cp != 0.0f) atomicAdd(&accp, cp);
  if (cn != 0.0f) atomicAdd(&accn, cn);
  if (rg != 0.0f) atomicAdd(&accr, rg);
  __syncthreads();
  if (threadIdx.x == 0) {
    if (accp != 0.0f) atomicAdd(&sums[b * 3 + 0], accp);
    if (accn != 0.0f) atomicAdd(&sums[b * 3 + 1], accn);
    if (accr != 0.0f) atomicAdd(&sums[b * 3 + 2], accr);
  }
}

// ---------- K5: finalize (parallel, 64 threads) ----------
__global__ void k_final(const float* __restrict__ sums,
                        const int* __restrict__ total_samples,
                        const int* __restrict__ num_pos,
                        float* __restrict__ out) {
  int t = threadIdx.x;
  float cm = 0.0f, rm = 0.0f;
  if (t < NB) {
    int ts = total_samples[t]; if (ts < 1) ts = 1;
    int np = num_pos[t]; if (np < 1) np = 1;
    cm = (sums[t * 3 + 0] + sums[t * 3 + 1]) / (float)ts;
    rm = sums[t * 3 + 2] / (float)np;
  }
  #pragma unroll
  for (int m = 8; m >= 1; m >>= 1) {
    cm += __shfl_down(cm, m, 64);
    rm += __shfl_down(rm, m, 64);
  }
  if (t == 0) out[0] = cm / (float)NB + rm / (float)NB;
}

extern "C" void kernel_launch(void* const* d_in, const int* in_sizes, int n_in,
                              void* d_out, int out_size, void* d_ws, size_t ws_size,
                              hipStream_t stream) {
  const float* cls     = (const float*)d_in[0];
  const float* reg     = (const float*)d_in[1];
  const float* anchors = (const float*)d_in[2];
  const float* tb      = (const float*)d_in[3];
  const int*   tl      = (const int*)d_in[4];
  const float* scores  = (const float*)d_in[5];
  float* out = (float*)d_out;

  char* ws = (char*)d_ws;
  size_t off = 0;
  float* miou = (float*)(ws + off);            off += (size_t)4 * NB * NANCH;
  int*   midx = (int*)(ws + off);              off += (size_t)4 * NB * NANCH;
  unsigned* qcb = (unsigned*)(ws + off);       off += (size_t)4 * NB * QCAP;
  int*   qci = (int*)(ws + off);               off += (size_t)4 * NB * QCAP;
  unsigned* scb = (unsigned*)(ws + off);       off += (size_t)4 * NB * SCAP;
  int*   sci = (int*)(ws + off);               off += (size_t)4 * NB * SCAP;
  int* scal = (int*)(ws + off);
  int* pos_cnt  = scal;                // zeroed block: 6*NB ints
  int* neg_cnt  = scal + NB;
  int* qcnt     = scal + 2 * NB;
  int* scnt     = scal + 3 * NB;
  int* flagq    = scal + 4 * NB;
  int* flags    = scal + 5 * NB;
  int* num_pos       = scal + 6 * NB;
  int* use_fb        = scal + 7 * NB;
  int* subsample     = scal + 8 * NB;
  int* idx_cut       = scal + 9 * NB;
  unsigned* vbits    = (unsigned*)(scal + 10 * NB);
  int* total_samples = scal + 11 * NB;
  int* top10         = scal + 12 * NB;                          // NB*10
  float* sums        = (float*)(scal + 12 * NB + MIN_POS_TOPK * NB); // NB*3

  k_zero<<<1, 256, 0, stream>>>(scal, sums);
  k_iou<<<NB * 128, IOU_TPB, 0, stream>>>(reg, anchors, tb, scores, miou, midx,
                                          pos_cnt, neg_cnt,
                                          qcb, qci, qcnt, scb, sci, scnt);
  k_sel<<<2 * NB, 1024, 0, stream>>>(qcb, qci, qcnt, scb, sci, scnt,
                                     pos_cnt, neg_cnt,
                                     num_pos, use_fb, subsample, total_samples,
                                     top10, vbits, idx_cut, flagq, flags);
  k_rescue<<<NB, 1024, 0, stream>>>(miou, scores, flagq, flags, num_pos,
                                    top10, vbits, idx_cut);
  k_loss<<<NB * 256, 256, 0, stream>>>(cls, reg, anchors, tb, tl, scores,
                                       miou, midx, use_fb, top10, subsample,
                                       vbits, idx_cut, sums);
  k_final<<<1, 64, 0, stream>>>(sums, total_samples, num_pos, out);
}

// Round 18
// 108.154 us; speedup vs baseline: 2.1377x; 2.1377x over previous
//
#include <hip/hip_runtime.h>
#include <math.h>
#include <limits.h>

#define NB 16
#define NC 21
#define NANCH 65536
#define NM 20

#define POS_THR 0.5f
#define NEG_THR 0.4f
#define F_ALPHA 0.25f
#define MIN_POS_TOPK 10
#define NEG_POS_RATIO 3

#define QT 0.125f        // top-10 candidate gather threshold (q >= QT)
#define ST 0.015625f     // neg-cut candidate gather threshold (score < 1/64)
#define QCAP 4096
#define SCAP 4096
#define APT 2
#define IOU_TPB 256

// ---------- K0: zero the small control block ----------
__global__ void k_zero(int* scal, float* sums) {
  int t = threadIdx.x;
  if (t < 6 * NB) scal[t] = 0;          // pos_cnt, neg_cnt, qcnt, scnt, flagq, flags
  if (t < 3 * NB) sums[t] = 0.0f;
}

// ---------- K1: pure decode + IoU max/argmax (R13 form, no atomics) ----------
__global__ __launch_bounds__(IOU_TPB)
void k_iou(const float* __restrict__ reg, const float* __restrict__ anchors,
           const float* __restrict__ tb,
           float* __restrict__ miou, int* __restrict__ midx) {
  __shared__ float4 tbs4[NM];
  __shared__ float  tarea[NM];
  int b   = blockIdx.x >> 7;           // 128 blocks per image
  int blk = blockIdx.x & 127;
  int n0  = (blk << 9) + threadIdx.x;  // 512 anchors per block
  if (threadIdx.x < NM) {
    float4 t4 = ((const float4*)tb)[b * NM + threadIdx.x];
    tbs4[threadIdx.x] = t4;
    tarea[threadIdx.x] = (t4.z - t4.x) * (t4.w - t4.y);
  }
  __syncthreads();

  float dv[APT][4];
  float areaA[APT];
  #pragma unroll
  for (int j = 0; j < APT; ++j) {
    int n = n0 + j * IOU_TPB;
    float4 a4 = ((const float4*)anchors)[n];
    float aw = a4.z - a4.x, ah = a4.w - a4.y;
    float acx = a4.x + 0.5f * aw, acy = a4.y + 0.5f * ah;
    size_t rb = ((size_t)b * 4) * NANCH + n;
    float rx = reg[rb];
    float ry = reg[rb + (size_t)NANCH];
    float rw = reg[rb + 2 * (size_t)NANCH];
    float rh = reg[rb + 3 * (size_t)NANCH];
    float cx = acx + rx * aw, cy = acy + ry * ah;
    float w = aw * expf(rw), h = ah * expf(rh);
    dv[j][0] = cx - 0.5f * w;
    dv[j][1] = cy - 0.5f * h;
    dv[j][2] = cx + 0.5f * w;
    dv[j][3] = cy + 0.5f * h;
    areaA[j] = (dv[j][2] - dv[j][0]) * (dv[j][3] - dv[j][1]);
  }

  float bI[APT], bU[APT];
  int   bM[APT];
  {
    float4 t = tbs4[0];
    float ab = tarea[0];
    #pragma unroll
    for (int j = 0; j < APT; ++j) {
      float lx = fmaxf(dv[j][0], t.x), ly = fmaxf(dv[j][1], t.y);
      float rx2 = fminf(dv[j][2], t.z), ry2 = fminf(dv[j][3], t.w);
      float iw = fmaxf(rx2 - lx, 0.0f), ih = fmaxf(ry2 - ly, 0.0f);
      float inter = iw * ih;
      bI[j] = inter;
      bU[j] = areaA[j] + ab - inter;
      bM[j] = 0;
    }
  }
  #pragma unroll
  for (int m = 1; m < NM; ++m) {
    float4 t = tbs4[m];
    float ab = tarea[m];
    #pragma unroll
    for (int j = 0; j < APT; ++j) {
      float lx = fmaxf(dv[j][0], t.x), ly = fmaxf(dv[j][1], t.y);
      float rx2 = fminf(dv[j][2], t.z), ry2 = fminf(dv[j][3], t.w);
      float iw = fmaxf(rx2 - lx, 0.0f), ih = fmaxf(ry2 - ly, 0.0f);
      float inter = iw * ih;
      float uni = areaA[j] + ab - inter;
      // inter/uni > bI/bU  <=>  inter*bU > bI*uni (both unions > 0)
      if (inter * bU[j] > bI[j] * uni) { bI[j] = inter; bU[j] = uni; bM[j] = m; }
    }
  }

  #pragma unroll
  for (int j = 0; j < APT; ++j) {
    int n = n0 + j * IOU_TPB;
    size_t idx = (size_t)b * NANCH + n;
    miou[idx] = bI[j] / fmaxf(bU[j], 1e-7f);   // IEEE, matches reference
    midx[idx] = bM[j];
  }
}

// wave-aggregated append into an LDS list: one LDS atomic per wave
__device__ __forceinline__ void wave_append_lds(bool want, int lane,
                                                int* cnt, unsigned* kb, int* ki,
                                                unsigned bits, int n) {
  unsigned long long m = __ballot(want);
  if (!m) return;
  int leader = __ffsll((long long)m) - 1;
  int base = 0;
  if (lane == leader) base = atomicAdd(cnt, __popcll(m));
  base = __shfl(base, leader, 64);
  if (want) {
    int slot = base + __popcll(m & ((1ULL << lane) - 1ULL));
    kb[slot] = bits; ki[slot] = n;    // slot < 1024 guaranteed (block covers 1024 anchors)
  }
}

// ---------- K2: counts + candidate gathers (block-aggregated; ablation-isolated) ----------
__global__ __launch_bounds__(1024)
void k_gather(const float* __restrict__ miou, const float* __restrict__ scores,
              int* __restrict__ pos_cnt, int* __restrict__ neg_cnt,
              unsigned* __restrict__ qcb, int* __restrict__ qci, int* __restrict__ qcnt,
              unsigned* __restrict__ scb, int* __restrict__ sci, int* __restrict__ scnt) {
  __shared__ unsigned lqB[1024];
  __shared__ int      lqI[1024];
  __shared__ unsigned lsB[1024];
  __shared__ int      lsI[1024];
  __shared__ int lqc, lsc, qbase, sbase;
  __shared__ int redp[16], redn[16];
  int b = blockIdx.x >> 6;                        // 64 blocks per image
  int n = ((blockIdx.x & 63) << 10) | threadIdx.x;
  if (threadIdx.x == 0) { lqc = 0; lsc = 0; }
  __syncthreads();

  size_t idx = (size_t)b * NANCH + n;
  float q = miou[idx];
  float s = scores[idx];
  bool p  = (q >= POS_THR);
  bool ng = (q < NEG_THR);
  int lane = threadIdx.x & 63;
  int wid  = threadIdx.x >> 6;
  int cp = __popcll(__ballot(p));
  int cn = __popcll(__ballot(ng));
  if (lane == 0) { redp[wid] = cp; redn[wid] = cn; }

  wave_append_lds(q >= QT, lane, &lqc, lqB, lqI, __float_as_uint(q), n);
  wave_append_lds(ng && s < ST, lane, &lsc, lsB, lsI, __float_as_uint(s), n);
  __syncthreads();

  if (threadIdx.x == 0) {
    int tp = 0, tn = 0;
    for (int w = 0; w < 16; ++w) { tp += redp[w]; tn += redn[w]; }
    if (tp) atomicAdd(&pos_cnt[b], tp);
    if (tn) atomicAdd(&neg_cnt[b], tn);
    qbase = lqc ? atomicAdd(&qcnt[b], lqc) : 0;
    sbase = lsc ? atomicAdd(&scnt[b], lsc) : 0;
  }
  __syncthreads();

  for (int j = threadIdx.x; j < lqc; j += 1024) {
    int slot = qbase + j;
    if (slot < QCAP) {
      qcb[(size_t)b * QCAP + slot] = lqB[j];
      qci[(size_t)b * QCAP + slot] = lqI[j];
    }
  }
  for (int j = threadIdx.x; j < lsc; j += 1024) {
    int slot = sbase + j;
    if (slot < SCAP) {
      scb[(size_t)b * SCAP + slot] = lsB[j];
      sci[(size_t)b * SCAP + slot] = lsI[j];
    }
  }
}

// bitonic ascending sort of key[0..S) in LDS, S = pow2, 1024 threads
__device__ __forceinline__ void bitonic_sort(unsigned long long* key, int S) {
  for (int kk = 2; kk <= S; kk <<= 1) {
    for (int jj = kk >> 1; jj > 0; jj >>= 1) {
      for (int i = threadIdx.x; i < S; i += 1024) {
        int ixj = i ^ jj;
        if (ixj > i) {
          bool up = ((i & kk) == 0);
          unsigned long long a = key[i], c = key[ixj];
          if ((a > c) == up) { key[i] = c; key[ixj] = a; }
        }
      }
      __syncthreads();
    }
  }
}

// ---------- K3: blocks 0..15 exact top-10 (bitonic), 16..31 exact neg cut (bitonic) ----------
__global__ __launch_bounds__(1024)
void k_sel(const unsigned* __restrict__ qcb, const int* __restrict__ qci,
           const int* __restrict__ qcnt,
           const unsigned* __restrict__ scb, const int* __restrict__ sci,
           const int* __restrict__ scnt,
           const int* __restrict__ pos_cnt, const int* __restrict__ neg_cnt,
           int* __restrict__ num_pos, int* __restrict__ use_fb,
           int* __restrict__ subsample, int* __restrict__ total_samples,
           int* __restrict__ top10,
           unsigned* __restrict__ vbits_out, int* __restrict__ idx_cut,
           int* __restrict__ flagq, int* __restrict__ flags) {
  __shared__ unsigned long long key[QCAP];
  if (blockIdx.x < NB) {
    int b = blockIdx.x;
    int pc = pos_cnt[b], nc = neg_cnt[b];
    int fb = (pc < MIN_POS_TOPK) ? 1 : 0;
    int np = fb ? MIN_POS_TOPK : pc;
    int k = NEG_POS_RATIO * np;
    int sub = (nc > k) ? 1 : 0;
    if (threadIdx.x == 0) {
      num_pos[b] = np; use_fb[b] = fb; subsample[b] = sub;
      total_samples[b] = sub ? (np + k) : (np + nc);
    }
    if (!fb) return;                       // top10 unused by k_loss
    int E = qcnt[b];
    if (E < MIN_POS_TOPK || E > QCAP) {    // candidate set insufficient -> rescue
      if (threadIdx.x == 0) flagq[b] = 1;
      return;
    }
    int S = 16; while (S < E) S <<= 1;
    for (int j = threadIdx.x; j < S; j += 1024) {
      key[j] = (j < E)
        ? ((unsigned long long)(~qcb[(size_t)b * QCAP + j]) << 32) | (unsigned)qci[(size_t)b * QCAP + j]
        : 0xFFFFFFFFFFFFFFFFULL;
    }
    __syncthreads();
    bitonic_sort(key, S);
    if (threadIdx.x < MIN_POS_TOPK)
      top10[b * MIN_POS_TOPK + threadIdx.x] = (int)(unsigned)(key[threadIdx.x] & 0xFFFFFFFFu);
  } else {
    int b = blockIdx.x - NB;
    int pc = pos_cnt[b], nc = neg_cnt[b];
    int np = (pc < MIN_POS_TOPK) ? MIN_POS_TOPK : pc;
    int k = NEG_POS_RATIO * np;
    if (nc <= k) {
      if (threadIdx.x == 0) { vbits_out[b] = 0u; idx_cut[b] = -1; }
      return;
    }
    int E = scnt[b];
    if (E < k || E > SCAP) {               // candidate set insufficient -> rescue
      if (threadIdx.x == 0) flags[b] = 1;
      return;
    }
    int S = 16; while (S < E) S <<= 1;
    for (int j = threadIdx.x; j < S; j += 1024) {
      key[j] = (j < E)
        ? ((unsigned long long)scb[(size_t)b * SCAP + j] << 32) | (unsigned)sci[(size_t)b * SCAP + j]
        : 0xFFFFFFFFFFFFFFFFULL;
    }
    __syncthreads();
    bitonic_sort(key, S);
    if (threadIdx.x == 0) {
      unsigned long long kv = key[k - 1];
      vbits_out[b] = (unsigned)(kv >> 32);
      idx_cut[b]  = (int)(unsigned)(kv & 0xFFFFFFFFu);
    }
  }
}

// ---------- K4: exact rescue for flagged images (early-exits when none) ----------
__global__ __launch_bounds__(1024)
void k_rescue(const float* __restrict__ miou, const float* __restrict__ scores,
              const int* __restrict__ flagq, const int* __restrict__ flags,
              const int* __restrict__ num_pos,
              int* __restrict__ top10,
              unsigned* __restrict__ vbits_out, int* __restrict__ idx_cut) {
  int b = blockIdx.x;
  int fq = flagq[b], fs = flags[b];
  if (!fq && !fs) return;
  const float* mi = miou + (size_t)b * NANCH;
  const float* sc = scores + (size_t)b * NANCH;
  int lane = threadIdx.x & 63;
  int wid  = threadIdx.x >> 6;

  __shared__ unsigned long long buf64[4096];   // shared by both phases
  __shared__ unsigned qh[64];
  __shared__ int s_thr, s_cnt, s_ok;

  if (fq) {
    // adaptive threshold: tightest t with #{q_bin64 >= t} >= 10, count <= 4096
    if (threadIdx.x < 64) qh[threadIdx.x] = 0u;
    if (threadIdx.x == 0) { s_cnt = 0; s_ok = 0; }
    __syncthreads();
    for (int n = threadIdx.x; n < NANCH; n += 1024) {
      float q = mi[n];
      if (q >= QT) {
        unsigned bin = (unsigned)(q * 64.0f);
        if (bin > 63u) bin = 63u;
        atomicAdd(&qh[bin], 1u);
      }
    }
    __syncthreads();
    if (threadIdx.x == 0) {
      unsigned cum = 0; int t = -1;
      for (int i = 63; i >= 8; --i) {          // largest t with suffix >= 10
        cum += qh[i];
        if (cum >= (unsigned)MIN_POS_TOPK) { t = i; break; }
      }
      if (t < 0) t = 8;
      unsigned c = 0;
      for (int i = t; i < 64; ++i) c += qh[i];
      s_thr = t; s_cnt = 0;
      s_ok = (c >= (unsigned)MIN_POS_TOPK && c <= 4096u) ? 1 : 0;
    }
    __syncthreads();
    if (s_ok) {
      int t = s_thr;
      for (int n = threadIdx.x; n < NANCH; n += 1024) {
        float q = mi[n];
        if (q >= QT) {
          unsigned bin = (unsigned)(q * 64.0f);
          if (bin > 63u) bin = 63u;
          if ((int)bin >= t) {
            int slot = atomicAdd(&s_cnt, 1);
            if (slot < 4096)
              buf64[slot] = ((unsigned long long)(~__float_as_uint(q)) << 32) | (unsigned)n;
          }
        }
      }
      __syncthreads();
      int E = s_cnt < 4096 ? s_cnt : 4096;
      int S = 16; while (S < E) S <<= 1;
      for (int j = threadIdx.x; j < S; j += 1024)
        if (j >= E) buf64[j] = 0xFFFFFFFFFFFFFFFFULL;
      __syncthreads();
      bitonic_sort(buf64, S);
      if (threadIdx.x < MIN_POS_TOPK)
        top10[b * MIN_POS_TOPK + threadIdx.x] = (int)(unsigned)(buf64[threadIdx.x] & 0xFFFFFFFFu);
    } else {
      // ultra-fallback (structurally ~never): exact 10-iteration scan
      __shared__ float fsv[16];
      __shared__ int   fsi[16];
      __shared__ int   fsel[MIN_POS_TOPK];
      for (int it = 0; it < MIN_POS_TOPK; ++it) {
        float bv = -1.0f; int bi = NANCH;
        for (int n = threadIdx.x; n < NANCH; n += 1024) {
          bool skip = false;
          for (int s2 = 0; s2 < it; ++s2) if (fsel[s2] == n) skip = true;
          if (skip) continue;
          float v = mi[n];
          if (v > bv || (v == bv && n < bi)) { bv = v; bi = n; }
        }
        #pragma unroll
        for (int m = 32; m >= 1; m >>= 1) {
          float ov = __shfl_xor(bv, m, 64);
          int   oi = __shfl_xor(bi, m, 64);
          if (ov > bv || (ov == bv && oi < bi)) { bv = ov; bi = oi; }
        }
        if (lane == 0) { fsv[wid] = bv; fsi[wid] = bi; }
        __syncthreads();
        if (threadIdx.x == 0) {
          float bb = -1.0f; int bj = NANCH;
          for (int w = 0; w < 16; ++w)
            if (fsv[w] > bb || (fsv[w] == bb && fsi[w] < bj)) { bb = fsv[w]; bj = fsi[w]; }
          fsel[it] = bj;
        }
        __syncthreads();
      }
      if (threadIdx.x < MIN_POS_TOPK) top10[b * MIN_POS_TOPK + threadIdx.x] = fsel[threadIdx.x];
    }
    __syncthreads();
  }

  if (fs) {
    // exact neg cut via 256-bin value hist, then bitonic over the boundary bucket
    __shared__ unsigned lsh[256];
    __shared__ int s_bkt, s_below, s_cnt2;
    int k = NEG_POS_RATIO * num_pos[b];
    if (threadIdx.x < 256) lsh[threadIdx.x] = 0u;
    if (threadIdx.x == 0) s_cnt2 = 0;
    __syncthreads();
    for (int n = threadIdx.x; n < NANCH; n += 1024) {
      if (mi[n] < NEG_THR) {
        unsigned bin = (unsigned)(sc[n] * 256.0f);
        if (bin > 255u) bin = 255u;
        atomicAdd(&lsh[bin], 1u);
      }
    }
    __syncthreads();
    if (threadIdx.x == 0) {
      unsigned cum = 0; int bkt = 255;
      for (int t = 0; t < 256; ++t) {
        if (cum + lsh[t] >= (unsigned)k) { bkt = t; break; }
        cum += lsh[t];
      }
      s_bkt = bkt; s_below = (int)cum;
    }
    __syncthreads();
    int bkt = s_bkt;
    for (int n = threadIdx.x; n < NANCH; n += 1024) {
      if (mi[n] < NEG_THR) {
        float s = sc[n];
        unsigned bin = (unsigned)(s * 256.0f);
        if (bin > 255u) bin = 255u;
        if ((int)bin == bkt) {
          int slot = atomicAdd(&s_cnt2, 1);
          if (slot < 4096)
            buf64[slot] = ((unsigned long long)__float_as_uint(s) << 32) | (unsigned)n;
        }
      }
    }
    __syncthreads();
    int E = s_cnt2 < 4096 ? s_cnt2 : 4096;
    int S = 16; while (S < E) S <<= 1;
    for (int j = threadIdx.x; j < S; j += 1024)
      if (j >= E) buf64[j] = 0xFFFFFFFFFFFFFFFFULL;
    __syncthreads();
    bitonic_sort(buf64, S);
    int r = k - s_below;                 // 1-based rank within bucket
    if (threadIdx.x == 0 && r >= 1 && r <= E) {
      unsigned long long kv = buf64[r - 1];
      vbits_out[b] = (unsigned)(kv >> 32);
      idx_cut[b]  = (int)(unsigned)(kv & 0xFFFFFFFFu);
    }
  }
}

// ---------- K5: per-anchor loss accumulation ----------
__global__ __launch_bounds__(256)
void k_loss(const float* __restrict__ cls, const float* __restrict__ reg,
            const float* __restrict__ anchors, const float* __restrict__ tb,
            const int* __restrict__ tl, const float* __restrict__ scores,
            const float* __restrict__ miou, const int* __restrict__ midx,
            const int* __restrict__ use_fb, const int* __restrict__ top10,
            const int* __restrict__ subsample, const unsigned* __restrict__ vbits,
            const int* __restrict__ idx_cut,
            float* __restrict__ sums /* [NB][3] : pos, neg, reg */) {
  int b = blockIdx.x >> 8;
  int n = ((blockIdx.x & 255) << 8) | threadIdx.x;
  __shared__ int s_top10[MIN_POS_TOPK];
  __shared__ int s_usefb, s_sub, s_cut;
  __shared__ unsigned s_vb;
  __shared__ float accp, accn, accr;
  if (threadIdx.x < MIN_POS_TOPK) s_top10[threadIdx.x] = top10[b * MIN_POS_TOPK + threadIdx.x];
  if (threadIdx.x == 0) {
    s_usefb = use_fb[b]; s_sub = subsample[b]; s_cut = idx_cut[b]; s_vb = vbits[b];
    accp = 0.0f; accn = 0.0f; accr = 0.0f;
  }
  __syncthreads();

  size_t idx = (size_t)b * NANCH + n;
  float mi = miou[idx];

  bool pos;
  if (s_usefb) {
    pos = false;
    #pragma unroll
    for (int i = 0; i < MIN_POS_TOPK; ++i) pos |= (s_top10[i] == n);
  } else {
    pos = (mi >= POS_THR);
  }
  bool neg = (mi < NEG_THR);
  bool nsel = false;
  if (neg) {
    if (!s_sub) nsel = true;
    else {
      unsigned sb = __float_as_uint(scores[idx]);
      nsel = (sb < s_vb) || (sb == s_vb && n <= s_cut);
    }
  }

  float cp = 0.0f, cn = 0.0f, rg = 0.0f;
  if (pos || nsel) {
    int mx = 0, t = 0;
    if (pos) { mx = midx[idx]; t = tl[b * NM + mx]; }
    size_t cb = ((size_t)b * NC) * NANCH + n;
    float mxl = -3.0e38f, l0 = 0.0f, lt = 0.0f;
    for (int c = 0; c < NC; ++c) {
      float l = cls[cb + (size_t)c * NANCH];
      if (c == 0) l0 = l;
      if (c == t) lt = l;
      mxl = fmaxf(mxl, l);
    }
    float se = 0.0f;
    for (int c = 0; c < NC; ++c) {
      float l = cls[cb + (size_t)c * NANCH];
      se += expf(l - mxl);
    }
    float lse = mxl + logf(se);
    if (nsel) {
      float ce = lse - l0;
      float pt = expf(-ce);
      float om = 1.0f - pt;
      cn = F_ALPHA * om * om * ce;
    }
    if (pos) {
      float ce = lse - lt;
      float pt = expf(-ce);
      float om = 1.0f - pt;
      cp = F_ALPHA * om * om * ce;
      // decode + GIoU vs matched GT
      const float4 a4 = ((const float4*)anchors)[n];
      float aw = a4.z - a4.x, ah = a4.w - a4.y;
      float acx = a4.x + 0.5f * aw, acy = a4.y + 0.5f * ah;
      size_t rb = ((size_t)b * 4) * NANCH + n;
      float rx = reg[rb];
      float ry = reg[rb + (size_t)NANCH];
      float rw = reg[rb + 2 * (size_t)NANCH];
      float rh = reg[rb + 3 * (size_t)NANCH];
      float ccx = acx + rx * aw, ccy = acy + ry * ah;
      float w = aw * expf(rw), h = ah * expf(rh);
      float d0 = ccx - 0.5f * w, d1 = ccy - 0.5f * h;
      float d2 = ccx + 0.5f * w, d3 = ccy + 0.5f * h;
      const float* g = tb + ((size_t)b * NM + mx) * 4;
      float gx1 = g[0], gy1 = g[1], gx2 = g[2], gy2 = g[3];
      float area_a = (d2 - d0) * (d3 - d1);
      float area_b = (gx2 - gx1) * (gy2 - gy1);
      float lx = fmaxf(d0, gx1), ly = fmaxf(d1, gy1);
      float rx2 = fminf(d2, gx2), ry2 = fminf(d3, gy2);
      float iw = fmaxf(rx2 - lx, 0.0f), ih = fmaxf(ry2 - ly, 0.0f);
      float inter = iw * ih;
      float uni = area_a + area_b - inter;
      float iou = inter / fmaxf(uni, 1e-7f);
      float ex1 = fminf(d0, gx1), ey1 = fminf(d1, gy1);
      float ex2 = fmaxf(d2, gx2), ey2 = fmaxf(d3, gy2);
      float ew = fmaxf(ex2 - ex1, 0.0f), eh = fmaxf(ey2 - ey1, 0.0f);
      float enc = ew * eh;
      float giou = iou - (enc - uni) / fmaxf(enc, 1e-7f);
      rg = 1.0f - giou;
    }
  }

  if (cp != 0.0f) atomicAdd(&accp, cp);
  if (cn != 0.0f) atomicAdd(&accn, cn);
  if (rg != 0.0f) atomicAdd(&accr, rg);
  __syncthreads();
  if (threadIdx.x == 0) {
    if (accp != 0.0f) atomicAdd(&sums[b * 3 + 0], accp);
    if (accn != 0.0f) atomicAdd(&sums[b * 3 + 1], accn);
    if (accr != 0.0f) atomicAdd(&sums[b * 3 + 2], accr);
  }
}

// ---------- K6: finalize (parallel, 64 threads) ----------
__global__ void k_final(const float* __restrict__ sums,
                        const int* __restrict__ total_samples,
                        const int* __restrict__ num_pos,
                        float* __restrict__ out) {
  int t = threadIdx.x;
  float cm = 0.0f, rm = 0.0f;
  if (t < NB) {
    int ts = total_samples[t]; if (ts < 1) ts = 1;
    int np = num_pos[t]; if (np < 1) np = 1;
    cm = (sums[t * 3 + 0] + sums[t * 3 + 1]) / (float)ts;
    rm = sums[t * 3 + 2] / (float)np;
  }
  #pragma unroll
  for (int m = 8; m >= 1; m >>= 1) {
    cm += __shfl_down(cm, m, 64);
    rm += __shfl_down(rm, m, 64);
  }
  if (t == 0) out[0] = cm / (float)NB + rm / (float)NB;
}

extern "C" void kernel_launch(void* const* d_in, const int* in_sizes, int n_in,
                              void* d_out, int out_size, void* d_ws, size_t ws_size,
                              hipStream_t stream) {
  const float* cls     = (const float*)d_in[0];
  const float* reg     = (const float*)d_in[1];
  const float* anchors = (const float*)d_in[2];
  const float* tb      = (const float*)d_in[3];
  const int*   tl      = (const int*)d_in[4];
  const float* scores  = (const float*)d_in[5];
  float* out = (float*)d_out;

  char* ws = (char*)d_ws;
  size_t off = 0;
  float* miou = (float*)(ws + off);            off += (size_t)4 * NB * NANCH;
  int*   midx = (int*)(ws + off);              off += (size_t)4 * NB * NANCH;
  unsigned* qcb = (unsigned*)(ws + off);       off += (size_t)4 * NB * QCAP;
  int*   qci = (int*)(ws + off);               off += (size_t)4 * NB * QCAP;
  unsigned* scb = (unsigned*)(ws + off);       off += (size_t)4 * NB * SCAP;
  int*   sci = (int*)(ws + off);               off += (size_t)4 * NB * SCAP;
  int* scal = (int*)(ws + off);
  int* pos_cnt  = scal;                // zeroed block: 6*NB ints
  int* neg_cnt  = scal + NB;
  int* qcnt     = scal + 2 * NB;
  int* scnt     = scal + 3 * NB;
  int* flagq    = scal + 4 * NB;
  int* flags    = scal + 5 * NB;
  int* num_pos       = scal + 6 * NB;
  int* use_fb        = scal + 7 * NB;
  int* subsample     = scal + 8 * NB;
  int* idx_cut       = scal + 9 * NB;
  unsigned* vbits    = (unsigned*)(scal + 10 * NB);
  int* total_samples = scal + 11 * NB;
  int* top10         = scal + 12 * NB;                          // NB*10
  float* sums        = (float*)(scal + 12 * NB + MIN_POS_TOPK * NB); // NB*3

  k_zero<<<1, 256, 0, stream>>>(scal, sums);
  k_iou<<<NB * 128, IOU_TPB, 0, stream>>>(reg, anchors, tb, miou, midx);
  k_gather<<<NB * 64, 1024, 0, stream>>>(miou, scores, pos_cnt, neg_cnt,
                                         qcb, qci, qcnt, scb, sci, scnt);
  k_sel<<<2 * NB, 1024, 0, stream>>>(qcb, qci, qcnt, scb, sci, scnt,
                                     pos_cnt, neg_cnt,
                                     num_pos, use_fb, subsample, total_samples,
                                     top10, vbits, idx_cut, flagq, flags);
  k_rescue<<<NB, 1024, 0, stream>>>(miou, scores, flagq, flags, num_pos,
                                    top10, vbits, idx_cut);
  k_loss<<<NB * 256, 256, 0, stream>>>(cls, reg, anchors, tb, tl, scores,
                                       miou, midx, use_fb, top10, subsample,
                                       vbits, idx_cut, sums);
  k_final<<<1, 64, 0, stream>>>(sums, total_samples, num_pos, out);
}

// Round 19
// 84.567 us; speedup vs baseline: 2.7339x; 1.2789x over previous
//
#include <hip/hip_runtime.h>
#include <math.h>
#include <limits.h>

#define NB 16
#define NC 21
#define NANCH 65536
#define NM 20

#define POS_THR 0.5f
#define NEG_THR 0.4f
#define F_ALPHA 0.25f
#define MIN_POS_TOPK 10
#define NEG_POS_RATIO 3

#define QT 0.125f        // top-10 candidate gather threshold (q >= QT)
#define ST 0.015625f     // neg-cut candidate gather threshold (score < 1/64)
#define QCAP 4096
#define SCAP 4096
#define BCAP 512         // boundary-bucket cap in k_sel neg path
#define APT 2
#define IOU_TPB 256

// ---------- K0: zero the small control block ----------
__global__ void k_zero(int* scal, float* sums) {
  int t = threadIdx.x;
  if (t < 6 * NB) scal[t] = 0;          // pos_cnt, neg_cnt, qcnt, scnt, flagq, flags
  if (t < 3 * NB) sums[t] = 0.0f;
}

// ---------- K1: pure decode + IoU max/argmax (no atomics) ----------
__global__ __launch_bounds__(IOU_TPB)
void k_iou(const float* __restrict__ reg, const float* __restrict__ anchors,
           const float* __restrict__ tb,
           float* __restrict__ miou, int* __restrict__ midx) {
  __shared__ float4 tbs4[NM];
  __shared__ float  tarea[NM];
  int b   = blockIdx.x >> 7;           // 128 blocks per image
  int blk = blockIdx.x & 127;
  int n0  = (blk << 9) + threadIdx.x;  // 512 anchors per block
  if (threadIdx.x < NM) {
    float4 t4 = ((const float4*)tb)[b * NM + threadIdx.x];
    tbs4[threadIdx.x] = t4;
    tarea[threadIdx.x] = (t4.z - t4.x) * (t4.w - t4.y);
  }
  __syncthreads();

  float dv[APT][4];
  float areaA[APT];
  #pragma unroll
  for (int j = 0; j < APT; ++j) {
    int n = n0 + j * IOU_TPB;
    float4 a4 = ((const float4*)anchors)[n];
    float aw = a4.z - a4.x, ah = a4.w - a4.y;
    float acx = a4.x + 0.5f * aw, acy = a4.y + 0.5f * ah;
    size_t rb = ((size_t)b * 4) * NANCH + n;
    float rx = reg[rb];
    float ry = reg[rb + (size_t)NANCH];
    float rw = reg[rb + 2 * (size_t)NANCH];
    float rh = reg[rb + 3 * (size_t)NANCH];
    float cx = acx + rx * aw, cy = acy + ry * ah;
    float w = aw * expf(rw), h = ah * expf(rh);
    dv[j][0] = cx - 0.5f * w;
    dv[j][1] = cy - 0.5f * h;
    dv[j][2] = cx + 0.5f * w;
    dv[j][3] = cy + 0.5f * h;
    areaA[j] = (dv[j][2] - dv[j][0]) * (dv[j][3] - dv[j][1]);
  }

  float bI[APT], bU[APT];
  int   bM[APT];
  {
    float4 t = tbs4[0];
    float ab = tarea[0];
    #pragma unroll
    for (int j = 0; j < APT; ++j) {
      float lx = fmaxf(dv[j][0], t.x), ly = fmaxf(dv[j][1], t.y);
      float rx2 = fminf(dv[j][2], t.z), ry2 = fminf(dv[j][3], t.w);
      float iw = fmaxf(rx2 - lx, 0.0f), ih = fmaxf(ry2 - ly, 0.0f);
      float inter = iw * ih;
      bI[j] = inter;
      bU[j] = areaA[j] + ab - inter;
      bM[j] = 0;
    }
  }
  #pragma unroll
  for (int m = 1; m < NM; ++m) {
    float4 t = tbs4[m];
    float ab = tarea[m];
    #pragma unroll
    for (int j = 0; j < APT; ++j) {
      float lx = fmaxf(dv[j][0], t.x), ly = fmaxf(dv[j][1], t.y);
      float rx2 = fminf(dv[j][2], t.z), ry2 = fminf(dv[j][3], t.w);
      float iw = fmaxf(rx2 - lx, 0.0f), ih = fmaxf(ry2 - ly, 0.0f);
      float inter = iw * ih;
      float uni = areaA[j] + ab - inter;
      // inter/uni > bI/bU  <=>  inter*bU > bI*uni (both unions > 0)
      if (inter * bU[j] > bI[j] * uni) { bI[j] = inter; bU[j] = uni; bM[j] = m; }
    }
  }

  #pragma unroll
  for (int j = 0; j < APT; ++j) {
    int n = n0 + j * IOU_TPB;
    size_t idx = (size_t)b * NANCH + n;
    miou[idx] = bI[j] / fmaxf(bU[j], 1e-7f);   // IEEE, matches reference
    midx[idx] = bM[j];
  }
}

// wave-aggregated append into an LDS list: one LDS atomic per wave
__device__ __forceinline__ void wave_append_lds(bool want, int lane,
                                                int* cnt, unsigned* kb, int* ki,
                                                unsigned bits, int n) {
  unsigned long long m = __ballot(want);
  if (!m) return;
  int leader = __ffsll((long long)m) - 1;
  int base = 0;
  if (lane == leader) base = atomicAdd(cnt, __popcll(m));
  base = __shfl(base, leader, 64);
  if (want) {
    int slot = base + __popcll(m & ((1ULL << lane) - 1ULL));
    kb[slot] = bits; ki[slot] = n;    // slot < 1024 guaranteed (block covers 1024 anchors)
  }
}

// ---------- K2: counts + candidate gathers (block-aggregated) ----------
__global__ __launch_bounds__(1024)
void k_gather(const float* __restrict__ miou, const float* __restrict__ scores,
              int* __restrict__ pos_cnt, int* __restrict__ neg_cnt,
              unsigned* __restrict__ qcb, int* __restrict__ qci, int* __restrict__ qcnt,
              unsigned* __restrict__ scb, int* __restrict__ sci, int* __restrict__ scnt) {
  __shared__ unsigned lqB[1024];
  __shared__ int      lqI[1024];
  __shared__ unsigned lsB[1024];
  __shared__ int      lsI[1024];
  __shared__ int lqc, lsc, qbase, sbase;
  __shared__ int redp[16], redn[16];
  int b = blockIdx.x >> 6;                        // 64 blocks per image
  int n = ((blockIdx.x & 63) << 10) | threadIdx.x;
  if (threadIdx.x == 0) { lqc = 0; lsc = 0; }
  __syncthreads();

  size_t idx = (size_t)b * NANCH + n;
  float q = miou[idx];
  float s = scores[idx];
  bool p  = (q >= POS_THR);
  bool ng = (q < NEG_THR);
  int lane = threadIdx.x & 63;
  int wid  = threadIdx.x >> 6;
  int cp = __popcll(__ballot(p));
  int cn = __popcll(__ballot(ng));
  if (lane == 0) { redp[wid] = cp; redn[wid] = cn; }

  wave_append_lds(q >= QT, lane, &lqc, lqB, lqI, __float_as_uint(q), n);
  wave_append_lds(ng && s < ST, lane, &lsc, lsB, lsI, __float_as_uint(s), n);
  __syncthreads();

  if (threadIdx.x == 0) {
    int tp = 0, tn = 0;
    for (int w = 0; w < 16; ++w) { tp += redp[w]; tn += redn[w]; }
    if (tp) atomicAdd(&pos_cnt[b], tp);
    if (tn) atomicAdd(&neg_cnt[b], tn);
    qbase = lqc ? atomicAdd(&qcnt[b], lqc) : 0;
    sbase = lsc ? atomicAdd(&scnt[b], lsc) : 0;
  }
  __syncthreads();

  for (int j = threadIdx.x; j < lqc; j += 1024) {
    int slot = qbase + j;
    if (slot < QCAP) {
      qcb[(size_t)b * QCAP + slot] = lqB[j];
      qci[(size_t)b * QCAP + slot] = lqI[j];
    }
  }
  for (int j = threadIdx.x; j < lsc; j += 1024) {
    int slot = sbase + j;
    if (slot < SCAP) {
      scb[(size_t)b * SCAP + slot] = lsB[j];
      sci[(size_t)b * SCAP + slot] = lsI[j];
    }
  }
}

// ---------- K3: blocks 0..15 top-10 via 10x argmax, 16..31 neg cut via sub-hist ----------
__global__ __launch_bounds__(1024)
void k_sel(const unsigned* __restrict__ qcb, const int* __restrict__ qci,
           const int* __restrict__ qcnt,
           const unsigned* __restrict__ scb, const int* __restrict__ sci,
           const int* __restrict__ scnt,
           const int* __restrict__ pos_cnt, const int* __restrict__ neg_cnt,
           int* __restrict__ num_pos, int* __restrict__ use_fb,
           int* __restrict__ subsample, int* __restrict__ total_samples,
           int* __restrict__ top10,
           unsigned* __restrict__ vbits_out, int* __restrict__ idx_cut,
           int* __restrict__ flagq, int* __restrict__ flags) {
  if (blockIdx.x < NB) {
    // ---------- top-10 by iterative argmax (bits desc, idx asc) ----------
    __shared__ unsigned cB[QCAP];
    __shared__ int      cI[QCAP];
    __shared__ unsigned wv[16];
    __shared__ int      wi[16], wsl[16];
    __shared__ int      sel[MIN_POS_TOPK];
    int b = blockIdx.x;
    int pc = pos_cnt[b], nc = neg_cnt[b];
    int fb = (pc < MIN_POS_TOPK) ? 1 : 0;
    int np = fb ? MIN_POS_TOPK : pc;
    int k = NEG_POS_RATIO * np;
    int sub = (nc > k) ? 1 : 0;
    if (threadIdx.x == 0) {
      num_pos[b] = np; use_fb[b] = fb; subsample[b] = sub;
      total_samples[b] = sub ? (np + k) : (np + nc);
    }
    if (!fb) return;                       // top10 unused by k_loss
    int E = qcnt[b];
    if (E < MIN_POS_TOPK || E > QCAP) {    // candidate set insufficient -> rescue
      if (threadIdx.x == 0) flagq[b] = 1;
      return;
    }
    for (int j = threadIdx.x; j < E; j += 1024) {
      cB[j] = qcb[(size_t)b * QCAP + j];   // all > 0 (q >= QT)
      cI[j] = qci[(size_t)b * QCAP + j];
    }
    __syncthreads();
    int lane = threadIdx.x & 63;
    int wid  = threadIdx.x >> 6;
    for (int it = 0; it < MIN_POS_TOPK; ++it) {
      unsigned bb = 0u; int bi = INT_MAX, bs = -1;
      for (int j = threadIdx.x; j < E; j += 1024) {
        unsigned v = cB[j];
        if (v > bb || (v == bb && cI[j] < bi)) { bb = v; bi = cI[j]; bs = j; }
      }
      #pragma unroll
      for (int m = 32; m >= 1; m >>= 1) {
        unsigned ov = __shfl_xor(bb, m, 64);
        int oi = __shfl_xor(bi, m, 64);
        int os = __shfl_xor(bs, m, 64);
        if (ov > bb || (ov == bb && oi < bi)) { bb = ov; bi = oi; bs = os; }
      }
      if (lane == 0) { wv[wid] = bb; wi[wid] = bi; wsl[wid] = bs; }
      __syncthreads();
      if (threadIdx.x == 0) {
        unsigned eb = 0u; int ei = INT_MAX, es = -1;
        for (int w = 0; w < 16; ++w) {
          if (wv[w] > eb || (wv[w] == eb && wi[w] < ei)) { eb = wv[w]; ei = wi[w]; es = wsl[w]; }
        }
        sel[it] = ei;
        cB[es] = 0u;                      // remove winner (real bits always > 0)
      }
      __syncthreads();
    }
    if (threadIdx.x < MIN_POS_TOPK) top10[b * MIN_POS_TOPK + threadIdx.x] = sel[threadIdx.x];
  } else {
    // ---------- exact neg cut via 256-bin sub-hist of [0, ST) ----------
    __shared__ unsigned hist[256];
    __shared__ unsigned bbB[BCAP];
    __shared__ int      bbI[BCAP];
    __shared__ int s_bkt, s_below, s_cnt;
    int b = blockIdx.x - NB;
    int pc = pos_cnt[b], nc = neg_cnt[b];
    int np = (pc < MIN_POS_TOPK) ? MIN_POS_TOPK : pc;
    int k = NEG_POS_RATIO * np;
    if (nc <= k) {
      if (threadIdx.x == 0) { vbits_out[b] = 0u; idx_cut[b] = -1; }
      return;
    }
    int E = scnt[b];
    if (E < k || E > SCAP) {               // candidate set insufficient -> rescue
      if (threadIdx.x == 0) flags[b] = 1;
      return;
    }
    if (threadIdx.x < 256) hist[threadIdx.x] = 0u;
    if (threadIdx.x == 0) s_cnt = 0;
    __syncthreads();
    // s < ST = 2^-6, so s * 2^14 < 256; exact (x2^14) & monotone binning
    for (int j = threadIdx.x; j < E; j += 1024) {
      float s = __uint_as_float(scb[(size_t)b * SCAP + j]);
      unsigned bin = (unsigned)(s * 16384.0f);
      atomicAdd(&hist[bin > 255u ? 255u : bin], 1u);
    }
    __syncthreads();
    if (threadIdx.x == 0) {
      unsigned cum = 0; int bkt = 255;
      for (int t = 0; t < 256; ++t) {
        if (cum + hist[t] >= (unsigned)k) { bkt = t; break; }
        cum += hist[t];
      }
      s_bkt = bkt; s_below = (int)cum;
    }
    __syncthreads();
    int bkt = s_bkt;
    for (int j = threadIdx.x; j < E; j += 1024) {
      unsigned sb = scb[(size_t)b * SCAP + j];
      float s = __uint_as_float(sb);
      unsigned bin = (unsigned)(s * 16384.0f);
      if ((int)(bin > 255u ? 255u : bin) == bkt) {
        int slot = atomicAdd(&s_cnt, 1);
        if (slot < BCAP) { bbB[slot] = sb; bbI[slot] = sci[(size_t)b * SCAP + j]; }
      }
    }
    __syncthreads();
    int cnt = s_cnt;
    int r = k - s_below;                   // 1-based rank within bucket
    if (cnt > BCAP || r < 1 || r > cnt) {  // overflow safety -> rescue (exact)
      if (threadIdx.x == 0) flags[b] = 1;
      return;
    }
    for (int e = threadIdx.x; e < cnt; e += 1024) {
      unsigned mb = bbB[e]; int mi_ = bbI[e];
      int rank = 0;
      for (int j = 0; j < cnt; ++j) {
        unsigned ob = bbB[j]; int oi = bbI[j];
        rank += (ob < mb || (ob == mb && oi < mi_)) ? 1 : 0;
      }
      if (rank == r - 1) { vbits_out[b] = mb; idx_cut[b] = mi_; }
    }
  }
}

// bitonic ascending sort of key[0..S) in LDS, S = pow2, 1024 threads (rescue only)
__device__ __forceinline__ void bitonic_sort(unsigned long long* key, int S) {
  for (int kk = 2; kk <= S; kk <<= 1) {
    for (int jj = kk >> 1; jj > 0; jj >>= 1) {
      for (int i = threadIdx.x; i < S; i += 1024) {
        int ixj = i ^ jj;
        if (ixj > i) {
          bool up = ((i & kk) == 0);
          unsigned long long a = key[i], c = key[ixj];
          if ((a > c) == up) { key[i] = c; key[ixj] = a; }
        }
      }
      __syncthreads();
    }
  }
}

// ---------- K4: exact rescue for flagged images (early-exits when none) ----------
__global__ __launch_bounds__(1024)
void k_rescue(const float* __restrict__ miou, const float* __restrict__ scores,
              const int* __restrict__ flagq, const int* __restrict__ flags,
              const int* __restrict__ num_pos,
              int* __restrict__ top10,
              unsigned* __restrict__ vbits_out, int* __restrict__ idx_cut) {
  int b = blockIdx.x;
  int fq = flagq[b], fs = flags[b];
  if (!fq && !fs) return;
  const float* mi = miou + (size_t)b * NANCH;
  const float* sc = scores + (size_t)b * NANCH;
  int lane = threadIdx.x & 63;
  int wid  = threadIdx.x >> 6;

  __shared__ unsigned long long buf64[4096];   // shared by both phases
  __shared__ unsigned qh[64];
  __shared__ int s_thr, s_cnt, s_ok;

  if (fq) {
    // adaptive threshold: tightest t with #{q_bin64 >= t} >= 10, count <= 4096
    if (threadIdx.x < 64) qh[threadIdx.x] = 0u;
    if (threadIdx.x == 0) { s_cnt = 0; s_ok = 0; }
    __syncthreads();
    for (int n = threadIdx.x; n < NANCH; n += 1024) {
      float q = mi[n];
      if (q >= QT) {
        unsigned bin = (unsigned)(q * 64.0f);
        if (bin > 63u) bin = 63u;
        atomicAdd(&qh[bin], 1u);
      }
    }
    __syncthreads();
    if (threadIdx.x == 0) {
      unsigned cum = 0; int t = -1;
      for (int i = 63; i >= 8; --i) {          // largest t with suffix >= 10
        cum += qh[i];
        if (cum >= (unsigned)MIN_POS_TOPK) { t = i; break; }
      }
      if (t < 0) t = 8;
      unsigned c = 0;
      for (int i = t; i < 64; ++i) c += qh[i];
      s_thr = t; s_cnt = 0;
      s_ok = (c >= (unsigned)MIN_POS_TOPK && c <= 4096u) ? 1 : 0;
    }
    __syncthreads();
    if (s_ok) {
      int t = s_thr;
      for (int n = threadIdx.x; n < NANCH; n += 1024) {
        float q = mi[n];
        if (q >= QT) {
          unsigned bin = (unsigned)(q * 64.0f);
          if (bin > 63u) bin = 63u;
          if ((int)bin >= t) {
            int slot = atomicAdd(&s_cnt, 1);
            if (slot < 4096)
              buf64[slot] = ((unsigned long long)(~__float_as_uint(q)) << 32) | (unsigned)n;
          }
        }
      }
      __syncthreads();
      int E = s_cnt < 4096 ? s_cnt : 4096;
      int S = 16; while (S < E) S <<= 1;
      for (int j = threadIdx.x; j < S; j += 1024)
        if (j >= E) buf64[j] = 0xFFFFFFFFFFFFFFFFULL;
      __syncthreads();
      bitonic_sort(buf64, S);
      if (threadIdx.x < MIN_POS_TOPK)
        top10[b * MIN_POS_TOPK + threadIdx.x] = (int)(unsigned)(buf64[threadIdx.x] & 0xFFFFFFFFu);
    } else {
      // ultra-fallback (structurally ~never): exact 10-iteration scan
      __shared__ float fsv[16];
      __shared__ int   fsi[16];
      __shared__ int   fsel[MIN_POS_TOPK];
      for (int it = 0; it < MIN_POS_TOPK; ++it) {
        float bv = -1.0f; int bi = NANCH;
        for (int n = threadIdx.x; n < NANCH; n += 1024) {
          bool skip = false;
          for (int s2 = 0; s2 < it; ++s2) if (fsel[s2] == n) skip = true;
          if (skip) continue;
          float v = mi[n];
          if (v > bv || (v == bv && n < bi)) { bv = v; bi = n; }
        }
        #pragma unroll
        for (int m = 32; m >= 1; m >>= 1) {
          float ov = __shfl_xor(bv, m, 64);
          int   oi = __shfl_xor(bi, m, 64);
          if (ov > bv || (ov == bv && oi < bi)) { bv = ov; bi = oi; }
        }
        if (lane == 0) { fsv[wid] = bv; fsi[wid] = bi; }
        __syncthreads();
        if (threadIdx.x == 0) {
          float bb = -1.0f; int bj = NANCH;
          for (int w = 0; w < 16; ++w)
            if (fsv[w] > bb || (fsv[w] == bb && fsi[w] < bj)) { bb = fsv[w]; bj = fsi[w]; }
          fsel[it] = bj;
        }
        __syncthreads();
      }
      if (threadIdx.x < MIN_POS_TOPK) top10[b * MIN_POS_TOPK + threadIdx.x] = fsel[threadIdx.x];
    }
    __syncthreads();
  }

  if (fs) {
    // exact neg cut via 256-bin value hist, then bitonic over the boundary bucket
    __shared__ unsigned lsh[256];
    __shared__ int s_bkt, s_below, s_cnt2;
    int k = NEG_POS_RATIO * num_pos[b];
    if (threadIdx.x < 256) lsh[threadIdx.x] = 0u;
    if (threadIdx.x == 0) s_cnt2 = 0;
    __syncthreads();
    for (int n = threadIdx.x; n < NANCH; n += 1024) {
      if (mi[n] < NEG_THR) {
        unsigned bin = (unsigned)(sc[n] * 256.0f);
        if (bin > 255u) bin = 255u;
        atomicAdd(&lsh[bin], 1u);
      }
    }
    __syncthreads();
    if (threadIdx.x == 0) {
      unsigned cum = 0; int bkt = 255;
      for (int t = 0; t < 256; ++t) {
        if (cum + lsh[t] >= (unsigned)k) { bkt = t; break; }
        cum += lsh[t];
      }
      s_bkt = bkt; s_below = (int)cum;
    }
    __syncthreads();
    int bkt = s_bkt;
    for (int n = threadIdx.x; n < NANCH; n += 1024) {
      if (mi[n] < NEG_THR) {
        float s = sc[n];
        unsigned bin = (unsigned)(s * 256.0f);
        if (bin > 255u) bin = 255u;
        if ((int)bin == bkt) {
          int slot = atomicAdd(&s_cnt2, 1);
          if (slot < 4096)
            buf64[slot] = ((unsigned long long)__float_as_uint(s) << 32) | (unsigned)n;
        }
      }
    }
    __syncthreads();
    int E = s_cnt2 < 4096 ? s_cnt2 : 4096;
    int S = 16; while (S < E) S <<= 1;
    for (int j = threadIdx.x; j < S; j += 1024)
      if (j >= E) buf64[j] = 0xFFFFFFFFFFFFFFFFULL;
    __syncthreads();
    bitonic_sort(buf64, S);
    int r = k - s_below;                 // 1-based rank within bucket
    if (threadIdx.x == 0 && r >= 1 && r <= E) {
      unsigned long long kv = buf64[r - 1];
      vbits_out[b] = (unsigned)(kv >> 32);
      idx_cut[b]  = (int)(unsigned)(kv & 0xFFFFFFFFu);
    }
  }
}

// ---------- K5: per-anchor loss accumulation ----------
__global__ __launch_bounds__(256)
void k_loss(const float* __restrict__ cls, const float* __restrict__ reg,
            const float* __restrict__ anchors, const float* __restrict__ tb,
            const int* __restrict__ tl, const float* __restrict__ scores,
            const float* __restrict__ miou, const int* __restrict__ midx,
            const int* __restrict__ use_fb, const int* __restrict__ top10,
            const int* __restrict__ subsample, const unsigned* __restrict__ vbits,
            const int* __restrict__ idx_cut,
            float* __restrict__ sums /* [NB][3] : pos, neg, reg */) {
  int b = blockIdx.x >> 8;
  int n = ((blockIdx.x & 255) << 8) | threadIdx.x;
  __shared__ int s_top10[MIN_POS_TOPK];
  __shared__ int s_usefb, s_sub, s_cut;
  __shared__ unsigned s_vb;
  __shared__ float accp, accn, accr;
  if (threadIdx.x < MIN_POS_TOPK) s_top10[threadIdx.x] = top10[b * MIN_POS_TOPK + threadIdx.x];
  if (threadIdx.x == 0) {
    s_usefb = use_fb[b]; s_sub = subsample[b]; s_cut = idx_cut[b]; s_vb = vbits[b];
    accp = 0.0f; accn = 0.0f; accr = 0.0f;
  }
  __syncthreads();

  size_t idx = (size_t)b * NANCH + n;
  float mi = miou[idx];

  bool pos;
  if (s_usefb) {
    pos = false;
    #pragma unroll
    for (int i = 0; i < MIN_POS_TOPK; ++i) pos |= (s_top10[i] == n);
  } else {
    pos = (mi >= POS_THR);
  }
  bool neg = (mi < NEG_THR);
  bool nsel = false;
  if (neg) {
    if (!s_sub) nsel = true;
    else {
      unsigned sb = __float_as_uint(scores[idx]);
      nsel = (sb < s_vb) || (sb == s_vb && n <= s_cut);
    }
  }

  float cp = 0.0f, cn = 0.0f, rg = 0.0f;
  if (pos || nsel) {
    int mx = 0, t = 0;
    if (pos) { mx = midx[idx]; t = tl[b * NM + mx]; }
    size_t cb = ((size_t)b * NC) * NANCH + n;
    float mxl = -3.0e38f, l0 = 0.0f, lt = 0.0f;
    for (int c = 0; c < NC; ++c) {
      float l = cls[cb + (size_t)c * NANCH];
      if (c == 0) l0 = l;
      if (c == t) lt = l;
      mxl = fmaxf(mxl, l);
    }
    float se = 0.0f;
    for (int c = 0; c < NC; ++c) {
      float l = cls[cb + (size_t)c * NANCH];
      se += expf(l - mxl);
    }
    float lse = mxl + logf(se);
    if (nsel) {
      float ce = lse - l0;
      float pt = expf(-ce);
      float om = 1.0f - pt;
      cn = F_ALPHA * om * om * ce;
    }
    if (pos) {
      float ce = lse - lt;
      float pt = expf(-ce);
      float om = 1.0f - pt;
      cp = F_ALPHA * om * om * ce;
      // decode + GIoU vs matched GT
      const float4 a4 = ((const float4*)anchors)[n];
      float aw = a4.z - a4.x, ah = a4.w - a4.y;
      float acx = a4.x + 0.5f * aw, acy = a4.y + 0.5f * ah;
      size_t rb = ((size_t)b * 4) * NANCH + n;
      float rx = reg[rb];
      float ry = reg[rb + (size_t)NANCH];
      float rw = reg[rb + 2 * (size_t)NANCH];
      float rh = reg[rb + 3 * (size_t)NANCH];
      float ccx = acx + rx * aw, ccy = acy + ry * ah;
      float w = aw * expf(rw), h = ah * expf(rh);
      float d0 = ccx - 0.5f * w, d1 = ccy - 0.5f * h;
      float d2 = ccx + 0.5f * w, d3 = ccy + 0.5f * h;
      const float* g = tb + ((size_t)b * NM + mx) * 4;
      float gx1 = g[0], gy1 = g[1], gx2 = g[2], gy2 = g[3];
      float area_a = (d2 - d0) * (d3 - d1);
      float area_b = (gx2 - gx1) * (gy2 - gy1);
      float lx = fmaxf(d0, gx1), ly = fmaxf(d1, gy1);
      float rx2 = fminf(d2, gx2), ry2 = fminf(d3, gy2);
      float iw = fmaxf(rx2 - lx, 0.0f), ih = fmaxf(ry2 - ly, 0.0f);
      float inter = iw * ih;
      float uni = area_a + area_b - inter;
      float iou = inter / fmaxf(uni, 1e-7f);
      float ex1 = fminf(d0, gx1), ey1 = fminf(d1, gy1);
      float ex2 = fmaxf(d2, gx2), ey2 = fmaxf(d3, gy2);
      float ew = fmaxf(ex2 - ex1, 0.0f), eh = fmaxf(ey2 - ey1, 0.0f);
      float enc = ew * eh;
      float giou = iou - (enc - uni) / fmaxf(enc, 1e-7f);
      rg = 1.0f - giou;
    }
  }

  if (cp != 0.0f) atomicAdd(&accp, cp);
  if (cn != 0.0f) atomicAdd(&accn, cn);
  if (rg != 0.0f) atomicAdd(&accr, rg);
  __syncthreads();
  if (threadIdx.x == 0) {
    if (accp != 0.0f) atomicAdd(&sums[b * 3 + 0], accp);
    if (accn != 0.0f) atomicAdd(&sums[b * 3 + 1], accn);
    if (accr != 0.0f) atomicAdd(&sums[b * 3 + 2], accr);
  }
}

// ---------- K6: finalize (parallel, 64 threads) ----------
__global__ void k_final(const float* __restrict__ sums,
                        const int* __restrict__ total_samples,
                        const int* __restrict__ num_pos,
                        float* __restrict__ out) {
  int t = threadIdx.x;
  float cm = 0.0f, rm = 0.0f;
  if (t < NB) {
    int ts = total_samples[t]; if (ts < 1) ts = 1;
    int np = num_pos[t]; if (np < 1) np = 1;
    cm = (sums[t * 3 + 0] + sums[t * 3 + 1]) / (float)ts;
    rm = sums[t * 3 + 2] / (float)np;
  }
  #pragma unroll
  for (int m = 8; m >= 1; m >>= 1) {
    cm += __shfl_down(cm, m, 64);
    rm += __shfl_down(rm, m, 64);
  }
  if (t == 0) out[0] = cm / (float)NB + rm / (float)NB;
}

extern "C" void kernel_launch(void* const* d_in, const int* in_sizes, int n_in,
                              void* d_out, int out_size, void* d_ws, size_t ws_size,
                              hipStream_t stream) {
  const float* cls     = (const float*)d_in[0];
  const float* reg     = (const float*)d_in[1];
  const float* anchors = (const float*)d_in[2];
  const float* tb      = (const float*)d_in[3];
  const int*   tl      = (const int*)d_in[4];
  const float* scores  = (const float*)d_in[5];
  float* out = (float*)d_out;

  char* ws = (char*)d_ws;
  size_t off = 0;
  float* miou = (float*)(ws + off);            off += (size_t)4 * NB * NANCH;
  int*   midx = (int*)(ws + off);              off += (size_t)4 * NB * NANCH;
  unsigned* qcb = (unsigned*)(ws + off);       off += (size_t)4 * NB * QCAP;
  int*   qci = (int*)(ws + off);               off += (size_t)4 * NB * QCAP;
  unsigned* scb = (unsigned*)(ws + off);       off += (size_t)4 * NB * SCAP;
  int*   sci = (int*)(ws + off);               off += (size_t)4 * NB * SCAP;
  int* scal = (int*)(ws + off);
  int* pos_cnt  = scal;                // zeroed block: 6*NB ints
  int* neg_cnt  = scal + NB;
  int* qcnt     = scal + 2 * NB;
  int* scnt     = scal + 3 * NB;
  int* flagq    = scal + 4 * NB;
  int* flags    = scal + 5 * NB;
  int* num_pos       = scal + 6 * NB;
  int* use_fb        = scal + 7 * NB;
  int* subsample     = scal + 8 * NB;
  int* idx_cut       = scal + 9 * NB;
  unsigned* vbits    = (unsigned*)(scal + 10 * NB);
  int* total_samples = scal + 11 * NB;
  int* top10         = scal + 12 * NB;                          // NB*10
  float* sums        = (float*)(scal + 12 * NB + MIN_POS_TOPK * NB); // NB*3

  k_zero<<<1, 256, 0, stream>>>(scal, sums);
  k_iou<<<NB * 128, IOU_TPB, 0, stream>>>(reg, anchors, tb, miou, midx);
  k_gather<<<NB * 64, 1024, 0, stream>>>(miou, scores, pos_cnt, neg_cnt,
                                         qcb, qci, qcnt, scb, sci, scnt);
  k_sel<<<2 * NB, 1024, 0, stream>>>(qcb, qci, qcnt, scb, sci, scnt,
                                     pos_cnt, neg_cnt,
                                     num_pos, use_fb, subsample, total_samples,
                                     top10, vbits, idx_cut, flagq, flags);
  k_rescue<<<NB, 1024, 0, stream>>>(miou, scores, flagq, flags, num_pos,
                                    top10, vbits, idx_cut);
  k_loss<<<NB * 256, 256, 0, stream>>>(cls, reg, anchors, tb, tl, scores,
                                       miou, midx, use_fb, top10, subsample,
                                       vbits, idx_cut, sums);
  k_final<<<1, 64, 0, stream>>>(sums, total_samples, num_pos, out);
}